// Round 2
// baseline (4673.693 us; speedup 1.0000x reference)
//
// Round 1: same algorithm as round 0, but batch-chunked (4 x 16 images) so peak
// workspace drops 267MB -> ~81MB — round-0 container crash was likely d_ws
// overflow. act3 chunk aliases act1 chunk slot (lifetimes disjoint in-stream).
// Pipeline: hist -> [per chunk: conv1 -> conv2 -> conv3 -> conv4] -> pool ->
// FC head -> broadcast. NHWC bf16 activations, fp32 accum, LDS-staged weights.
// Predicted: ~2.0-2.7ms, VALU-bound (MfmaUtil=0), absmax ~1e-3.
#include <hip/hip_runtime.h>

typedef unsigned short u16;

__device__ __forceinline__ float bf2f_lo(unsigned d){ return __uint_as_float(d << 16); }
__device__ __forceinline__ float bf2f_hi(unsigned d){ return __uint_as_float(d & 0xFFFF0000u); }
__device__ __forceinline__ float bf2f(u16 v){ return __uint_as_float(((unsigned)v) << 16); }
__device__ __forceinline__ u16 f2bf(float f){
  unsigned u = __float_as_uint(f);
  u += 0x7FFFu + ((u >> 16) & 1u);   // RNE
  return (u16)(u >> 16);
}
__device__ __forceinline__ unsigned pack2(float a, float b){
  return (unsigned)f2bf(a) | ((unsigned)f2bf(b) << 16);
}

constexpr int ilog2c(int v){ return v <= 1 ? 0 : 1 + ilog2c(v / 2); }

// ---------------- weight repack: OIHW fp32 -> [tap(16)][ci][co] fp32 ----------------
__global__ __launch_bounds__(256) void repack_w(const float* __restrict__ src,
                                                float* __restrict__ dst,
                                                int CI, int CO){
  int i = blockIdx.x * 256 + threadIdx.x;     // linear over src = [co][ci][16]
  int n = CO * CI * 16;
  if (i < n){
    int t  = i & 15;
    int r  = i >> 4;
    int ci = r % CI;
    int co = r / CI;
    dst[((size_t)t * CI + ci) * CO + co] = src[i];
  }
}

// ---------------- histogram: img [64][3][256][256] -> hist [192][16] normalized ----------------
__global__ __launch_bounds__(256) void hist_k(const float* __restrict__ img,
                                              float* __restrict__ hist){
  __shared__ float cnt[256 * 17];   // +1 pad breaks 16-stride bank conflicts
  __shared__ float bins[16];
  const int tid = threadIdx.x;
  const int bc  = blockIdx.x;       // b*3+c
  #pragma unroll
  for (int i = 0; i < 16; i++) cnt[tid * 17 + i] = 0.f;
  __syncthreads();
  const float* p = img + (size_t)bc * 65536;
  for (int i = tid; i < 65536; i += 256){
    float v = p[i];
    float x = (v + 1.f) * 0.5f;
    int idx = (int)floorf((x + 1.f) * 8.f);
    idx = min(max(idx, 0), 15);
    float inr = (x >= -1.f && x <= 1.f) ? 1.f : 0.f;
    cnt[tid * 17 + idx] += inr;
  }
  __syncthreads();
  if (tid < 16){
    float s = 0.f;
    for (int r = 0; r < 256; r++) s += cnt[r * 17 + tid];
    bins[tid] = s;
  }
  __syncthreads();
  if (tid < 16){
    float tot = 0.f;
    #pragma unroll
    for (int i = 0; i < 16; i++) tot += bins[i];
    hist[bc * 16 + tid] = bins[tid] / (tot + 1e-6f);
  }
}

// ---------------- conv1: img NCHW fp32 -> act1 [Bc][130][130][64] bf16 (zero halo) ------------
__global__ __launch_bounds__(256) void conv1_k(const float* __restrict__ img,
                                               const float* __restrict__ w1r,  // [16][3][64]
                                               const float* __restrict__ b1,
                                               u16* __restrict__ out){
  const int tid = threadIdx.x;
  const int oc  = tid & 63;
  const int pq  = tid >> 6;          // 0..3
  const int b   = blockIdx.y;        // within chunk
  const int pixBase = blockIdx.x * 32 + pq * 8;
  float w[48];
  #pragma unroll
  for (int i = 0; i < 48; i++) w[i] = w1r[i * 64 + oc];
  const float bias = b1[oc];
  const float* imb = img + (size_t)b * 3 * 65536;
  for (int p = 0; p < 8; p++){
    int pix = pixBase + p;
    int oh = pix >> 7, ow = pix & 127;
    float acc = bias;
    #pragma unroll
    for (int kh = 0; kh < 4; kh++){
      int ih = oh * 2 - 1 + kh;
      if ((unsigned)ih < 256u){
        #pragma unroll
        for (int kw = 0; kw < 4; kw++){
          int iw = ow * 2 - 1 + kw;
          if ((unsigned)iw < 256u){
            int off = ih * 256 + iw;
            int t = (kh * 4 + kw) * 3;
            acc += imb[off]          * w[t + 0];
            acc += imb[65536 + off]  * w[t + 1];
            acc += imb[131072 + off] * w[t + 2];
          }
        }
      }
    }
    float r = fmaxf(acc, 0.f);
    out[(((size_t)b * 130 + (oh + 1)) * 130 + (ow + 1)) * 64 + oc] = f2bf(r);
  }
}

// ---------------- generic stride-2 4x4 conv, NHWC bf16, fp32 accumulate ----------------
// in: [Bc][2HO+2][2WO+2][CI] zero-halo; wr: [16][CI][CO]; out: [Bc][HO+2*OPAD][WO+2*OPAD][CO]
template<int CI, int CO, int HO, int WO, int OCB, int OPAD>
__global__ __launch_bounds__(256) void conv_s2(const u16* __restrict__ in,
                                               const float* __restrict__ wr,
                                               const float* __restrict__ bias,
                                               u16* __restrict__ out){
  constexpr int HI  = 2 * HO + 2, WI = 2 * WO + 2;
  constexpr int OCG = OCB / 8;            // oc groups of 8
  constexpr int LG  = ilog2c(OCG);
  constexpr int PIXG = 256 / OCG;         // pixel groups of 4
  constexpr int PIX  = PIXG * 4;
  constexpr int HOP = HO + 2 * OPAD, WOP = WO + 2 * OPAD;
  extern __shared__ float wlds[];          // CI*OCB floats

  const int tid  = threadIdx.x;
  const int ocg  = tid & (OCG - 1);
  const int pixg = tid >> LG;
  const int b      = blockIdx.z;
  const int ocBase = blockIdx.y * OCB;
  const int oc0    = ocg * 8;              // within block oc tile
  const int pixBase = blockIdx.x * PIX + pixg * 4;

  int oh[4], ow[4];
  #pragma unroll
  for (int p = 0; p < 4; p++){ int pp = pixBase + p; oh[p] = pp / WO; ow[p] = pp % WO; }

  float acc[4][8];
  #pragma unroll
  for (int p = 0; p < 4; p++)
    #pragma unroll
    for (int o = 0; o < 8; o++) acc[p][o] = 0.f;

  for (int tap = 0; tap < 16; ++tap){
    const int kh = tap >> 2, kw = tap & 3;
    __syncthreads();
    {
      const float* wsrc = wr + (size_t)tap * CI * CO + ocBase;
      for (int i = tid; i < CI * OCB; i += 256){
        int ci = i / OCB, oc = i & (OCB - 1);
        wlds[i] = wsrc[(size_t)ci * CO + oc];
      }
    }
    __syncthreads();
    const u16* pin[4];
    #pragma unroll
    for (int p = 0; p < 4; p++){
      int ih = oh[p] * 2 + kh, iw = ow[p] * 2 + kw;   // already includes +1 pad offset
      pin[p] = in + ((size_t)(b * HI + ih) * WI + iw) * CI;
    }
    for (int c4 = 0; c4 < CI; c4 += 4){
      uint2 r[4];
      #pragma unroll
      for (int p = 0; p < 4; p++) r[p] = *(const uint2*)(pin[p] + c4);
      float v[4][4];
      #pragma unroll
      for (int p = 0; p < 4; p++){
        v[p][0] = bf2f_lo(r[p].x); v[p][1] = bf2f_hi(r[p].x);
        v[p][2] = bf2f_lo(r[p].y); v[p][3] = bf2f_hi(r[p].y);
      }
      #pragma unroll
      for (int j = 0; j < 4; j++){
        const float* wj = &wlds[(c4 + j) * OCB + oc0];
        float4 wa = *(const float4*)(wj);
        float4 wb = *(const float4*)(wj + 4);
        #pragma unroll
        for (int p = 0; p < 4; p++){
          acc[p][0] += v[p][j] * wa.x; acc[p][1] += v[p][j] * wa.y;
          acc[p][2] += v[p][j] * wa.z; acc[p][3] += v[p][j] * wa.w;
          acc[p][4] += v[p][j] * wb.x; acc[p][5] += v[p][j] * wb.y;
          acc[p][6] += v[p][j] * wb.z; acc[p][7] += v[p][j] * wb.w;
        }
      }
    }
  }
  float bs[8];
  #pragma unroll
  for (int o = 0; o < 8; o++) bs[o] = bias[ocBase + oc0 + o];
  #pragma unroll
  for (int p = 0; p < 4; p++){
    float rr[8];
    #pragma unroll
    for (int o = 0; o < 8; o++) rr[o] = fmaxf(acc[p][o] + bs[o], 0.f);
    uint4 st;
    st.x = pack2(rr[0], rr[1]); st.y = pack2(rr[2], rr[3]);
    st.z = pack2(rr[4], rr[5]); st.w = pack2(rr[6], rr[7]);
    u16* op = out + (((size_t)(b * HOP + oh[p] + OPAD) * WOP) + ow[p] + OPAD) * CO
                  + ocBase + oc0;
    *(uint4*)op = st;
  }
}

// ---------------- pool: act4 [64][16][16][512] bf16 -> pooled [64][512] fp32 ----------------
__global__ __launch_bounds__(512) void pool_k(const u16* __restrict__ act4,
                                              float* __restrict__ pooled){
  const int c = threadIdx.x;
  const int b = blockIdx.x;
  const u16* p = act4 + (size_t)b * 256 * 512 + c;
  float s = 0.f;
  for (int i = 0; i < 256; i++) s += bf2f(p[i * 512]);
  pooled[b * 512 + c] = s * (1.f / 256.f);
}

// ---------------- FC head: pooled+hist -> color_feat [64][3] ----------------
__global__ __launch_bounds__(64) void feat_k(const float* __restrict__ pooled,
                                             const float* __restrict__ hist,
                                             const float* __restrict__ wf, const float* __restrict__ bfv,
                                             const float* __restrict__ wh, const float* __restrict__ bh,
                                             const float* __restrict__ wo, const float* __restrict__ bo,
                                             float* __restrict__ cfeat){
  __shared__ float comb[128];
  const int j = threadIdx.x;
  const int b = blockIdx.x;
  const float* pb = pooled + b * 512;
  const float* wfj = wf + j * 512;
  float s = bfv[j];
  for (int k = 0; k < 512; k++) s += pb[k] * wfj[k];
  comb[j] = s;
  const float* hb = hist + b * 48;
  const float* whj = wh + j * 48;
  float t = bh[j];
  for (int k = 0; k < 48; k++) t += hb[k] * whj[k];
  comb[64 + j] = t;
  __syncthreads();
  if (j < 3){
    float c = bo[j];
    const float* woj = wo + j * 128;
    for (int k = 0; k < 128; k++) c += comb[k] * woj[k];
    cfeat[b * 3 + j] = c;
  }
}

// ---------------- broadcast color_feat -> out [64][3][256][256] fp32 ----------------
__global__ __launch_bounds__(256) void bcast_k(const float* __restrict__ cfeat,
                                               float* __restrict__ out){
  size_t i = (size_t)blockIdx.x * 256 + threadIdx.x;   // float4 index
  int bc = (int)(i >> 14);                              // 16384 float4 per (b,ch)
  float v = cfeat[bc];
  float4 f = make_float4(v, v, v, v);
  ((float4*)out)[i] = f;
}

extern "C" void kernel_launch(void* const* d_in, const int* in_sizes, int n_in,
                              void* d_out, int out_size, void* d_ws, size_t ws_size,
                              hipStream_t stream){
  const float* img = (const float*)d_in[0];
  const float* w1  = (const float*)d_in[1];
  const float* b1  = (const float*)d_in[2];
  const float* w2  = (const float*)d_in[3];
  const float* b2  = (const float*)d_in[4];
  const float* w3  = (const float*)d_in[5];
  const float* b3  = (const float*)d_in[6];
  const float* w4  = (const float*)d_in[7];
  const float* b4  = (const float*)d_in[8];
  const float* wf  = (const float*)d_in[9];
  const float* bfv = (const float*)d_in[10];
  const float* wh  = (const float*)d_in[11];
  const float* bh  = (const float*)d_in[12];
  const float* wo  = (const float*)d_in[13];
  const float* bo  = (const float*)d_in[14];
  float* out = (float*)d_out;

  char* ws = (char*)d_ws;
  size_t off = 0;
  auto alloc = [&](size_t bytes) -> void* {
    void* p = ws + off;
    off += (bytes + 255) & ~(size_t)255;
    return p;
  };
  // Per-chunk (Bc=16) activations; act3 aliases act1 (disjoint lifetimes).
  constexpr int BC = 16;                                 // batch chunk
  const size_t A1c = (size_t)BC * 130 * 130 * 64 * 2;    // 34.6 MB
  const size_t A2c = (size_t)BC * 66 * 66 * 128 * 2;     // 17.8 MB
  const size_t A3c = (size_t)BC * 34 * 34 * 256 * 2;     //  9.5 MB (fits in A1c)
  const size_t A4  = (size_t)64 * 16 * 16 * 512 * 2;     // 16.8 MB (full batch)
  u16*   act1 = (u16*)  alloc(A1c);
  u16*   act2 = (u16*)  alloc(A2c);
  u16*   act3 = act1;                                    // alias
  u16*   act4 = (u16*)  alloc(A4);
  float* w1r  = (float*)alloc((size_t)16 * 3 * 64 * 4);
  float* w2r  = (float*)alloc((size_t)16 * 64 * 128 * 4);
  float* w3r  = (float*)alloc((size_t)16 * 128 * 256 * 4);
  float* w4r  = (float*)alloc((size_t)16 * 256 * 512 * 4);   // 8.4 MB
  float* hist   = (float*)alloc((size_t)64 * 48 * 4);
  float* pooled = (float*)alloc((size_t)64 * 512 * 4);
  float* cfeat  = (float*)alloc((size_t)64 * 3 * 4);
  // peak ~81 MB; (void)ws_size — layout is static and small.
  (void)ws_size; (void)in_sizes; (void)n_in; (void)out_size;

  // repack weights OIHW -> [tap][ci][co]  (once; before any chunk)
  repack_w<<<dim3((64 * 3 * 16 + 255) / 256), 256, 0, stream>>>(w1, w1r, 3, 64);
  repack_w<<<dim3((128 * 64 * 16) / 256), 256, 0, stream>>>(w2, w2r, 64, 128);
  repack_w<<<dim3((256 * 128 * 16) / 256), 256, 0, stream>>>(w3, w3r, 128, 256);
  repack_w<<<dim3((512 * 256 * 16) / 256), 256, 0, stream>>>(w4, w4r, 256, 512);

  hist_k<<<dim3(192), 256, 0, stream>>>(img, hist);

  for (int c = 0; c < 64 / BC; ++c){
    const float* img_c  = img  + (size_t)c * BC * 3 * 65536;
    u16*         act4_c = act4 + (size_t)c * BC * 256 * 512;

    // zero halos (full padded chunk buffers; halo-only zeroing is a later opt)
    hipMemsetAsync(act1, 0, A1c, stream);
    conv1_k<<<dim3(512, BC), 256, 0, stream>>>(img_c, w1r, b1, act1);

    hipMemsetAsync(act2, 0, A2c, stream);
    // conv2: 64->128, 64x64 out
    conv_s2<64, 128, 64, 64, 64, 1>
        <<<dim3(32, 2, BC), 256, 64 * 64 * 4, stream>>>(act1, w2r, b2, act2);

    hipMemsetAsync(act3, 0, A3c, stream);   // aliases act1; stream order is safe
    // conv3: 128->256, 32x32 out
    conv_s2<128, 256, 32, 32, 64, 1>
        <<<dim3(8, 4, BC), 256, 128 * 64 * 4, stream>>>(act2, w3r, b3, act3);

    // conv4: 256->512, 16x16 out, unpadded output
    conv_s2<256, 512, 16, 16, 32, 0>
        <<<dim3(1, 16, BC), 256, 256 * 32 * 4, stream>>>(act3, w4r, b4, act4_c);
  }

  pool_k<<<dim3(64), 512, 0, stream>>>(act4, pooled);
  feat_k<<<dim3(64), 64, 0, stream>>>(pooled, hist, wf, bfv, wh, bh, wo, bo, cfeat);
  bcast_k<<<dim3(12288), 256, 0, stream>>>(cfeat, out);
}

// Round 4
// 1495.249 us; speedup vs baseline: 3.1257x; 3.1257x over previous
//
// Round 3: MFMA implicit-GEMM for conv2-4, HARDENED: no global_load_lds
// (uint4 global->reg->ds_write_b128 staging, m93-style), no ws tier branch
// (exact round-2-passed memory plan, ~72MB, fully chunked BC=16).
// Isolates round-2 crash cause: if this passes, the DMA/tier path was at fault;
// if it crashes too, infra flake. Predicted: ~1100-1400us, MfmaUtil 20-40%.
#include <hip/hip_runtime.h>

typedef unsigned short u16;
typedef __attribute__((ext_vector_type(8))) short bf16x8;   // 8 bf16 (4 VGPRs)
typedef __attribute__((ext_vector_type(4))) float f32x4;

__device__ __forceinline__ float bf2f(u16 v){ return __uint_as_float(((unsigned)v) << 16); }
__device__ __forceinline__ u16 f2bf(float f){
  unsigned u = __float_as_uint(f);
  u += 0x7FFFu + ((u >> 16) & 1u);   // RNE
  return (u16)(u >> 16);
}

// ---------------- weight repacks ----------------
// conv1: OIHW fp32 -> [tap][ci][co] fp32
__global__ __launch_bounds__(256) void repack_w1(const float* __restrict__ src,
                                                 float* __restrict__ dst){
  int i = blockIdx.x * 256 + threadIdx.x;     // over [64][3][16]
  if (i < 64 * 3 * 16){
    int t  = i & 15;
    int r  = i >> 4;
    int ci = r % 3;
    int co = r / 3;
    dst[(t * 3 + ci) * 64 + co] = src[i];
  }
}
// conv2-4: OIHW fp32 -> [tap][co][ci] bf16 (B^T / [N][K] layout for MFMA)
__global__ __launch_bounds__(256) void repack_w_bf(const float* __restrict__ src,
                                                   u16* __restrict__ dst,
                                                   int CI, int CO){
  int i = blockIdx.x * 256 + threadIdx.x;     // linear over src = [co][ci][16]
  if (i < CO * CI * 16){
    int t  = i & 15;
    int r  = i >> 4;
    int ci = r & (CI - 1);
    int co = r / CI;
    dst[((size_t)t * CO + co) * CI + ci] = f2bf(src[i]);
  }
}

// ---------------- histogram ----------------
__global__ __launch_bounds__(256) void hist_k(const float* __restrict__ img,
                                              float* __restrict__ hist){
  __shared__ float cnt[256 * 17];
  __shared__ float bins[16];
  const int tid = threadIdx.x;
  const int bc  = blockIdx.x;
  #pragma unroll
  for (int i = 0; i < 16; i++) cnt[tid * 17 + i] = 0.f;
  __syncthreads();
  const float* p = img + (size_t)bc * 65536;
  for (int i = tid; i < 65536; i += 256){
    float v = p[i];
    float x = (v + 1.f) * 0.5f;
    int idx = (int)floorf((x + 1.f) * 8.f);
    idx = min(max(idx, 0), 15);
    float inr = (x >= -1.f && x <= 1.f) ? 1.f : 0.f;
    cnt[tid * 17 + idx] += inr;
  }
  __syncthreads();
  if (tid < 16){
    float s = 0.f;
    for (int r = 0; r < 256; r++) s += cnt[r * 17 + tid];
    bins[tid] = s;
  }
  __syncthreads();
  if (tid < 16){
    float tot = 0.f;
    #pragma unroll
    for (int i = 0; i < 16; i++) tot += bins[i];
    hist[bc * 16 + tid] = bins[tid] / (tot + 1e-6f);
  }
}

// ---------------- conv1: NCHW fp32 -> [Bc][130][130][64] bf16 (zero halo) ----------------
__global__ __launch_bounds__(256) void conv1_k(const float* __restrict__ img,
                                               const float* __restrict__ w1r,  // [16][3][64]
                                               const float* __restrict__ b1,
                                               u16* __restrict__ out){
  const int tid = threadIdx.x;
  const int oc  = tid & 63;
  const int pq  = tid >> 6;
  const int b   = blockIdx.y;
  const int pixBase = blockIdx.x * 32 + pq * 8;
  float w[48];
  #pragma unroll
  for (int i = 0; i < 48; i++) w[i] = w1r[i * 64 + oc];
  const float bias = b1[oc];
  const float* imb = img + (size_t)b * 3 * 65536;
  for (int p = 0; p < 8; p++){
    int pix = pixBase + p;
    int oh = pix >> 7, ow = pix & 127;
    float acc = bias;
    #pragma unroll
    for (int kh = 0; kh < 4; kh++){
      int ih = oh * 2 - 1 + kh;
      if ((unsigned)ih < 256u){
        #pragma unroll
        for (int kw = 0; kw < 4; kw++){
          int iw = ow * 2 - 1 + kw;
          if ((unsigned)iw < 256u){
            int off = ih * 256 + iw;
            int t = (kh * 4 + kw) * 3;
            acc += imb[off]          * w[t + 0];
            acc += imb[65536 + off]  * w[t + 1];
            acc += imb[131072 + off] * w[t + 2];
          }
        }
      }
    }
    float r = fmaxf(acc, 0.f);
    out[(((size_t)b * 130 + (oh + 1)) * 130 + (ow + 1)) * 64 + oc] = f2bf(r);
  }
}

// ---------------- MFMA implicit-GEMM stride-2 4x4 conv (register-staged LDS) -------------
// in:  [B][2HO+2][2WO+2][CI] bf16, zero halo
// wr:  [16][CO][CI] bf16   (B^T / [N][K] layout)
// out: [B][HO+2*OPAD][WO+2*OPAD][CO] bf16, interior written, bias+relu fused
// GEMM view: M = B*HO*WO (%128==0), N = CO, K = 16*CI. 128x128 tile, 2x2 waves,
// each wave 4x4 16x16x32 frags. Staging: thread t loads 2x16B of A and B,
// ds_write_b128 into [row][32-elem] K-slab tiles.
template<int CI, int CO, int HO, int WO, int B, int OPAD>
__global__ __launch_bounds__(256, 2) void conv_mfma(const u16* __restrict__ in,
                                                    const u16* __restrict__ wr,
                                                    const float* __restrict__ bias,
                                                    u16* __restrict__ out){
  constexpr int HI  = 2 * HO + 2, WI = 2 * WO + 2;
  constexpr int HOP = HO + 2 * OPAD, WOP = WO + 2 * OPAD;
  constexpr int CC  = CI / 32;
  __shared__ __align__(16) u16 ldsA[128 * 32];
  __shared__ __align__(16) u16 ldsB[128 * 32];
  const int tid  = threadIdx.x;
  const int lane = tid & 63;
  const int w    = tid >> 6;
  const int quad = lane >> 4, l15 = lane & 15;
  const int wm = w & 1, wn = w >> 1;
  const int Mbase = blockIdx.x * 128;
  const int Nbase = blockIdx.y * 128;

  // staging map: thread t -> rows (t>>2) and (t>>2)+64, 16B chunk (t&3)
  const int srow = tid >> 2;
  const int sel  = (tid & 3) * 8;            // u16 elements within 32-elem row
  int apix[2], brow[2];
  #pragma unroll
  for (int i = 0; i < 2; i++){
    int p  = Mbase + srow + 64 * i;
    int b  = p / (HO * WO);
    int r  = p & (HO * WO - 1);
    int oh = r / WO, ow = r & (WO - 1);
    apix[i] = ((b * HI + 2 * oh) * WI + 2 * ow) * CI + sel;
    brow[i] = (Nbase + srow + 64 * i) * CI + sel;
  }
  const int lofs = srow * 32 + sel;

  f32x4 acc[4][4];
  #pragma unroll
  for (int i = 0; i < 4; i++)
    #pragma unroll
    for (int j = 0; j < 4; j++) acc[i][j] = (f32x4){0.f, 0.f, 0.f, 0.f};

  #pragma unroll 1
  for (int tap = 0; tap < 16; ++tap){
    const int kh = tap >> 2, kw = tap & 3;
    const int ad = (kh * WI + kw) * CI;      // tap shift in input
    const int bd = tap * CO * CI;            // tap slab in weights
    #pragma unroll 1
    for (int cc = 0; cc < CC; ++cc){
      const int ci0 = cc * 32;
      uint4 ra0 = *(const uint4*)(in + apix[0] + ad + ci0);
      uint4 ra1 = *(const uint4*)(in + apix[1] + ad + ci0);
      uint4 rb0 = *(const uint4*)(wr + brow[0] + bd + ci0);
      uint4 rb1 = *(const uint4*)(wr + brow[1] + bd + ci0);
      __syncthreads();                       // previous iter's readers done
      *(uint4*)(ldsA + lofs)        = ra0;
      *(uint4*)(ldsA + lofs + 2048) = ra1;
      *(uint4*)(ldsB + lofs)        = rb0;
      *(uint4*)(ldsB + lofs + 2048) = rb1;
      __syncthreads();                       // writes visible
      bf16x8 af[4], bfr[4];
      #pragma unroll
      for (int i = 0; i < 4; i++)
        af[i]  = *(const bf16x8*)(ldsA + (wm * 64 + i * 16 + l15) * 32 + quad * 8);
      #pragma unroll
      for (int j = 0; j < 4; j++)
        bfr[j] = *(const bf16x8*)(ldsB + (wn * 64 + j * 16 + l15) * 32 + quad * 8);
      #pragma unroll
      for (int i = 0; i < 4; i++)
        #pragma unroll
        for (int j = 0; j < 4; j++)
          acc[i][j] = __builtin_amdgcn_mfma_f32_16x16x32_bf16(af[i], bfr[j], acc[i][j], 0, 0, 0);
    }
  }

  // epilogue: bias + relu + bf16 store. C/D map: row(M)=quad*4+reg, col(N)=lane&15.
  float bv[4];
  #pragma unroll
  for (int j = 0; j < 4; j++) bv[j] = bias[Nbase + wn * 64 + j * 16 + l15];
  const int ncol = Nbase + wn * 64 + l15;
  #pragma unroll
  for (int i = 0; i < 4; i++){
    #pragma unroll
    for (int r = 0; r < 4; r++){
      int p  = Mbase + wm * 64 + i * 16 + quad * 4 + r;
      int b  = p / (HO * WO);
      int rr = p & (HO * WO - 1);
      int oh = rr / WO, ow = rr & (WO - 1);
      u16* op = out + (((size_t)b * HOP + oh + OPAD) * WOP + ow + OPAD) * CO + ncol;
      #pragma unroll
      for (int j = 0; j < 4; j++)
        op[j * 16] = f2bf(fmaxf(acc[i][j][r] + bv[j], 0.f));
    }
  }
}

// ---------------- pool ----------------
__global__ __launch_bounds__(512) void pool_k(const u16* __restrict__ act4,
                                              float* __restrict__ pooled){
  const int c = threadIdx.x;
  const int b = blockIdx.x;
  const u16* p = act4 + (size_t)b * 256 * 512 + c;
  float s = 0.f;
  for (int i = 0; i < 256; i++) s += bf2f(p[i * 512]);
  pooled[b * 512 + c] = s * (1.f / 256.f);
}

// ---------------- FC head ----------------
__global__ __launch_bounds__(64) void feat_k(const float* __restrict__ pooled,
                                             const float* __restrict__ hist,
                                             const float* __restrict__ wf, const float* __restrict__ bfv,
                                             const float* __restrict__ wh, const float* __restrict__ bh,
                                             const float* __restrict__ wo, const float* __restrict__ bo,
                                             float* __restrict__ cfeat){
  __shared__ float comb[128];
  const int j = threadIdx.x;
  const int b = blockIdx.x;
  const float* pb  = pooled + b * 512;
  const float* wfj = wf + j * 512;
  float s = bfv[j];
  for (int k = 0; k < 512; k++) s += pb[k] * wfj[k];
  comb[j] = s;
  const float* hb  = hist + b * 48;
  const float* whj = wh + j * 48;
  float t = bh[j];
  for (int k = 0; k < 48; k++) t += hb[k] * whj[k];
  comb[64 + j] = t;
  __syncthreads();
  if (j < 3){
    float c = bo[j];
    const float* woj = wo + j * 128;
    for (int k = 0; k < 128; k++) c += comb[k] * woj[k];
    cfeat[b * 3 + j] = c;
  }
}

// ---------------- broadcast ----------------
__global__ __launch_bounds__(256) void bcast_k(const float* __restrict__ cfeat,
                                               float* __restrict__ out){
  size_t i = (size_t)blockIdx.x * 256 + threadIdx.x;
  int bc = (int)(i >> 14);
  float v = cfeat[bc];
  ((float4*)out)[i] = make_float4(v, v, v, v);
}

extern "C" void kernel_launch(void* const* d_in, const int* in_sizes, int n_in,
                              void* d_out, int out_size, void* d_ws, size_t ws_size,
                              hipStream_t stream){
  const float* img = (const float*)d_in[0];
  const float* w1  = (const float*)d_in[1];
  const float* b1  = (const float*)d_in[2];
  const float* w2  = (const float*)d_in[3];
  const float* b2  = (const float*)d_in[4];
  const float* w3  = (const float*)d_in[5];
  const float* b3  = (const float*)d_in[6];
  const float* w4  = (const float*)d_in[7];
  const float* b4  = (const float*)d_in[8];
  const float* wf  = (const float*)d_in[9];
  const float* bfv = (const float*)d_in[10];
  const float* wh  = (const float*)d_in[11];
  const float* bh  = (const float*)d_in[12];
  const float* wo  = (const float*)d_in[13];
  const float* bo  = (const float*)d_in[14];
  float* out = (float*)d_out;
  (void)in_sizes; (void)n_in; (void)out_size; (void)ws_size;

  char* ws = (char*)d_ws;
  size_t off = 0;
  auto alloc = [&](size_t bytes) -> void* {
    void* p = ws + off;
    off += (bytes + 255) & ~(size_t)255;
    return p;
  };
  // Round-2-proven plan: fully chunked BC=16, slot shared by act1c/act3c. ~72MB peak.
  constexpr int BC = 16;
  const size_t A1c = (size_t)BC * 130 * 130 * 64 * 2;    // 34.6 MB
  const size_t A2c = (size_t)BC * 66 * 66 * 128 * 2;     // 17.8 MB
  const size_t A3c = (size_t)BC * 34 * 34 * 256 * 2;     //  9.5 MB (aliases slot)
  const size_t A4  = (size_t)64 * 16 * 16 * 512 * 2;     // 16.8 MB

  u16*   slot = (u16*)alloc(A1c);
  u16*   act2 = (u16*)alloc(A2c);
  u16*   act4 = (u16*)alloc(A4);
  float* w1r  = (float*)alloc((size_t)16 * 3 * 64 * 4);
  u16*   w2r  = (u16*)  alloc((size_t)16 * 128 * 64 * 2);
  u16*   w3r  = (u16*)  alloc((size_t)16 * 256 * 128 * 2);
  u16*   w4r  = (u16*)  alloc((size_t)16 * 512 * 256 * 2);
  float* hist   = (float*)alloc((size_t)64 * 48 * 4);
  float* pooled = (float*)alloc((size_t)64 * 512 * 4);
  float* cfeat  = (float*)alloc((size_t)64 * 3 * 4);

  repack_w1  <<<dim3(12), 256, 0, stream>>>(w1, w1r);
  repack_w_bf<<<dim3(512),  256, 0, stream>>>(w2, w2r, 64, 128);
  repack_w_bf<<<dim3(2048), 256, 0, stream>>>(w3, w3r, 128, 256);
  repack_w_bf<<<dim3(8192), 256, 0, stream>>>(w4, w4r, 256, 512);

  hist_k<<<dim3(192), 256, 0, stream>>>(img, hist);

  hipMemsetAsync(act2, 0, A2c, stream);   // halo zeroed once; interior rewritten per chunk
  for (int c = 0; c < 4; ++c){
    const float* img_c  = img  + (size_t)c * BC * 3 * 65536;
    u16*         act4_c = act4 + (size_t)c * BC * 256 * 512;

    hipMemsetAsync(slot, 0, A1c, stream);
    conv1_k<<<dim3(512, BC), 256, 0, stream>>>(img_c, w1r, b1, slot);
    // conv2: 64->128, M=65536 -> grid(512,1)
    conv_mfma<64, 128, 64, 64, BC, 1>
        <<<dim3(512, 1), 256, 0, stream>>>(slot, w2r, b2, act2);
    hipMemsetAsync(slot, 0, A3c, stream);   // act3c aliases slot
    // conv3: 128->256, M=16384 -> grid(128,2)
    conv_mfma<128, 256, 32, 32, BC, 1>
        <<<dim3(128, 2), 256, 0, stream>>>(act2, w3r, b3, slot);
    // conv4: 256->512, M=4096 -> grid(32,4)
    conv_mfma<256, 512, 16, 16, BC, 0>
        <<<dim3(32, 4), 256, 0, stream>>>(slot, w4r, b4, act4_c);
  }

  pool_k<<<dim3(64), 512, 0, stream>>>(act4, pooled);
  feat_k<<<dim3(64), 64, 0, stream>>>(pooled, hist, wf, bfv, wh, bh, wo, bo, cfeat);
  bcast_k<<<dim3(12288), 256, 0, stream>>>(cfeat, out);
}

// Round 5
// 1245.360 us; speedup vs baseline: 3.7529x; 1.2007x over previous
//
// Round 4: conv1 -> MFMA implicit-GEMM (img repacked to [Bc][258][258][4] bf16,
// K=64 = 4kh x 4kw x 4ci-padded; imgr aliases act2c -> footprint ~75MB, under
// the proven 81MB). conv_mfma generalized to wave-grid template; conv3 64x128
// (512 blocks) and conv4 64x64 (512 blocks) now fill the chip.
// Predicted: 1495 -> ~900-1100us; conv1_k gone from top-5; MfmaUtil 25-45%.
#include <hip/hip_runtime.h>

typedef unsigned short u16;
typedef __attribute__((ext_vector_type(8))) short bf16x8;   // 8 bf16 (4 VGPRs)
typedef __attribute__((ext_vector_type(4))) float f32x4;

__device__ __forceinline__ float bf2f(u16 v){ return __uint_as_float(((unsigned)v) << 16); }
__device__ __forceinline__ u16 f2bf(float f){
  unsigned u = __float_as_uint(f);
  u += 0x7FFFu + ((u >> 16) & 1u);   // RNE
  return (u16)(u >> 16);
}

constexpr int ilog2c(int v){ return v <= 1 ? 0 : 1 + ilog2c(v / 2); }

// ---------------- weight repacks ----------------
// conv1: OIHW fp32 [64][3][4][4] -> [co][k=kh*16+kw*4+ci] bf16, ci padded to 4 (zeros)
__global__ __launch_bounds__(256) void repack_w1m(const float* __restrict__ src,
                                                  u16* __restrict__ dst){
  int i = blockIdx.x * 256 + threadIdx.x;     // over [64][64]
  if (i < 64 * 64){
    int k  = i & 63, co = i >> 6;
    int kh = k >> 4, kw = (k >> 2) & 3, ci = k & 3;
    float v = (ci < 3) ? src[((co * 3 + ci) * 4 + kh) * 4 + kw] : 0.f;
    dst[i] = f2bf(v);
  }
}
// conv2-4: OIHW fp32 -> [tap][co][ci] bf16 (B^T / [N][K] layout for MFMA)
__global__ __launch_bounds__(256) void repack_w_bf(const float* __restrict__ src,
                                                   u16* __restrict__ dst,
                                                   int CI, int CO){
  int i = blockIdx.x * 256 + threadIdx.x;     // linear over src = [co][ci][16]
  if (i < CO * CI * 16){
    int t  = i & 15;
    int r  = i >> 4;
    int ci = r & (CI - 1);
    int co = r / CI;
    dst[((size_t)t * CO + co) * CI + ci] = f2bf(src[i]);
  }
}

// ---------------- img repack: NCHW fp32 (16 imgs) -> [16][258][258][4] bf16 ----------------
// halo ring pre-zeroed by memset; interior written here (ch3 = 0).
__global__ __launch_bounds__(256) void repack_img(const float* __restrict__ img,
                                                  u16* __restrict__ dst){
  int i = blockIdx.x * 256 + threadIdx.x;     // over 16*65536 pixels
  int b  = i >> 16;
  int r  = i & 65535;
  int ih = r >> 8, iw = r & 255;
  float c0 = img[((size_t)b * 3 + 0) * 65536 + r];
  float c1 = img[((size_t)b * 3 + 1) * 65536 + r];
  float c2 = img[((size_t)b * 3 + 2) * 65536 + r];
  ushort4 v = { f2bf(c0), f2bf(c1), f2bf(c2), 0 };
  *(ushort4*)(dst + ((size_t)(b * 258 + ih + 1) * 258 + iw + 1) * 4) = v;
}

// ---------------- histogram ----------------
__global__ __launch_bounds__(256) void hist_k(const float* __restrict__ img,
                                              float* __restrict__ hist){
  __shared__ float cnt[256 * 17];
  __shared__ float bins[16];
  const int tid = threadIdx.x;
  const int bc  = blockIdx.x;
  #pragma unroll
  for (int i = 0; i < 16; i++) cnt[tid * 17 + i] = 0.f;
  __syncthreads();
  const float* p = img + (size_t)bc * 65536;
  for (int i = tid; i < 65536; i += 256){
    float v = p[i];
    float x = (v + 1.f) * 0.5f;
    int idx = (int)floorf((x + 1.f) * 8.f);
    idx = min(max(idx, 0), 15);
    float inr = (x >= -1.f && x <= 1.f) ? 1.f : 0.f;
    cnt[tid * 17 + idx] += inr;
  }
  __syncthreads();
  if (tid < 16){
    float s = 0.f;
    for (int r = 0; r < 256; r++) s += cnt[r * 17 + tid];
    bins[tid] = s;
  }
  __syncthreads();
  if (tid < 16){
    float tot = 0.f;
    #pragma unroll
    for (int i = 0; i < 16; i++) tot += bins[i];
    hist[bc * 16 + tid] = bins[tid] / (tot + 1e-6f);
  }
}

// ---------------- conv1 MFMA: imgr [Bc][258][258][4] -> act1 [Bc][130][130][64] -----------
// GEMM: M = Bc*16384, N = 64, K = 64 (kh*16+kw*4+ci). TM=256 (4 waves x 4 frags),
// TN=64 (4 frags). Staging: thread t -> A rows (t>>2)+64i, 16B chunk c=(t&3):
// chunk c of slab cc = input row (2oh + 2cc + (c>>1)), cols 2ow+(c&1)*2 (2 px x 4ch).
__global__ __launch_bounds__(256, 2) void conv1_mfma(const u16* __restrict__ in,
                                                     const u16* __restrict__ wm1,  // [64][64]
                                                     const float* __restrict__ bias,
                                                     u16* __restrict__ out){
  __shared__ __align__(16) u16 ldsA[256 * 32];
  __shared__ __align__(16) u16 ldsB[64 * 32];
  const int tid  = threadIdx.x;
  const int lane = tid & 63;
  const int w    = tid >> 6;                 // wave = wm (0..3)
  const int quad = lane >> 4, l15 = lane & 15;
  const int Mbase = blockIdx.x * 256;

  const int srow = tid >> 2;
  const int c    = tid & 3;
  int a0[4];
  #pragma unroll
  for (int i = 0; i < 4; i++){
    int p  = Mbase + srow + 64 * i;
    int b  = p >> 14;
    int rr = p & 16383;
    int oh = rr >> 7, ow = rr & 127;
    a0[i] = ((b * 258 + 2 * oh + (c >> 1)) * 258 + 2 * ow + (c & 1) * 2) * 4;
  }
  const int b0 = srow * 64 + c * 8;

  f32x4 acc[4][4];
  #pragma unroll
  for (int i = 0; i < 4; i++)
    #pragma unroll
    for (int j = 0; j < 4; j++) acc[i][j] = (f32x4){0.f, 0.f, 0.f, 0.f};

  #pragma unroll
  for (int cc = 0; cc < 2; ++cc){
    uint4 ra[4];
    #pragma unroll
    for (int i = 0; i < 4; i++) ra[i] = *(const uint4*)(in + a0[i] + cc * 2064);
    uint4 rb = *(const uint4*)(wm1 + b0 + cc * 32);
    __syncthreads();
    #pragma unroll
    for (int i = 0; i < 4; i++)
      *(uint4*)(ldsA + (srow + 64 * i) * 32 + c * 8) = ra[i];
    *(uint4*)(ldsB + srow * 32 + c * 8) = rb;
    __syncthreads();
    bf16x8 af[4], bfr[4];
    #pragma unroll
    for (int i = 0; i < 4; i++)
      af[i]  = *(const bf16x8*)(ldsA + (w * 64 + i * 16 + l15) * 32 + quad * 8);
    #pragma unroll
    for (int j = 0; j < 4; j++)
      bfr[j] = *(const bf16x8*)(ldsB + (j * 16 + l15) * 32 + quad * 8);
    #pragma unroll
    for (int i = 0; i < 4; i++)
      #pragma unroll
      for (int j = 0; j < 4; j++)
        acc[i][j] = __builtin_amdgcn_mfma_f32_16x16x32_bf16(af[i], bfr[j], acc[i][j], 0, 0, 0);
  }

  float bv[4];
  #pragma unroll
  for (int j = 0; j < 4; j++) bv[j] = bias[j * 16 + l15];
  #pragma unroll
  for (int i = 0; i < 4; i++){
    #pragma unroll
    for (int r = 0; r < 4; r++){
      int p  = Mbase + w * 64 + i * 16 + quad * 4 + r;
      int b  = p >> 14;
      int rr = p & 16383;
      int oh = rr >> 7, ow = rr & 127;
      u16* op = out + ((size_t)(b * 130 + oh + 1) * 130 + ow + 1) * 64 + l15;
      #pragma unroll
      for (int j = 0; j < 4; j++)
        op[j * 16] = f2bf(fmaxf(acc[i][j][r] + bv[j], 0.f));
    }
  }
}

// ---------------- generic MFMA implicit-GEMM stride-2 4x4 conv ----------------
// in: [B][2HO+2][2WO+2][CI] bf16 zero-halo; wr: [16][CO][CI] bf16; out interior,
// bias+relu fused. Tile: TM=WM*FM*16 x TN=WN*FN*16; K-slab = 32 ch of one tap.
template<int CI, int CO, int HO, int WO, int OPAD, int WM, int WN, int FM, int FN>
__global__ __launch_bounds__(256, 2) void conv_mfma(const u16* __restrict__ in,
                                                    const u16* __restrict__ wr,
                                                    const float* __restrict__ bias,
                                                    u16* __restrict__ out){
  constexpr int HI  = 2 * HO + 2, WI = 2 * WO + 2;
  constexpr int HOP = HO + 2 * OPAD, WOP = WO + 2 * OPAD;
  constexpr int CC  = CI / 32;
  constexpr int TM  = WM * FM * 16, TN = WN * FN * 16;
  constexpr int ACH = TM / 64, BCH = TN / 64;          // 16B chunks per thread
  __shared__ __align__(16) u16 ldsA[TM * 32];
  __shared__ __align__(16) u16 ldsB[TN * 32];
  const int tid  = threadIdx.x;
  const int lane = tid & 63;
  const int w    = tid >> 6;
  const int quad = lane >> 4, l15 = lane & 15;
  const int wm = w & (WM - 1), wn = w >> ilog2c(WM);
  const int Mbase = blockIdx.x * TM;
  const int Nbase = blockIdx.y * TN;

  const int srow = tid >> 2;
  const int sel  = (tid & 3) * 8;
  int apix[ACH], brow[BCH];
  #pragma unroll
  for (int i = 0; i < ACH; i++){
    int p  = Mbase + srow + 64 * i;
    int b  = p / (HO * WO);
    int r  = p & (HO * WO - 1);
    int oh = r / WO, ow = r & (WO - 1);
    apix[i] = ((b * HI + 2 * oh) * WI + 2 * ow) * CI + sel;
  }
  #pragma unroll
  for (int i = 0; i < BCH; i++)
    brow[i] = (Nbase + srow + 64 * i) * CI + sel;

  f32x4 acc[FM][FN];
  #pragma unroll
  for (int i = 0; i < FM; i++)
    #pragma unroll
    for (int j = 0; j < FN; j++) acc[i][j] = (f32x4){0.f, 0.f, 0.f, 0.f};

  #pragma unroll 1
  for (int tap = 0; tap < 16; ++tap){
    const int kh = tap >> 2, kw = tap & 3;
    const int ad = (kh * WI + kw) * CI;
    const int bd = tap * CO * CI;
    #pragma unroll 1
    for (int cc = 0; cc < CC; ++cc){
      const int ci0 = cc * 32;
      uint4 ra[ACH], rb[BCH];
      #pragma unroll
      for (int i = 0; i < ACH; i++) ra[i] = *(const uint4*)(in + apix[i] + ad + ci0);
      #pragma unroll
      for (int i = 0; i < BCH; i++) rb[i] = *(const uint4*)(wr + brow[i] + bd + ci0);
      __syncthreads();
      #pragma unroll
      for (int i = 0; i < ACH; i++)
        *(uint4*)(ldsA + (srow + 64 * i) * 32 + sel) = ra[i];
      #pragma unroll
      for (int i = 0; i < BCH; i++)
        *(uint4*)(ldsB + (srow + 64 * i) * 32 + sel) = rb[i];
      __syncthreads();
      bf16x8 af[FM], bfr[FN];
      #pragma unroll
      for (int i = 0; i < FM; i++)
        af[i]  = *(const bf16x8*)(ldsA + ((wm * FM + i) * 16 + l15) * 32 + quad * 8);
      #pragma unroll
      for (int j = 0; j < FN; j++)
        bfr[j] = *(const bf16x8*)(ldsB + ((wn * FN + j) * 16 + l15) * 32 + quad * 8);
      #pragma unroll
      for (int i = 0; i < FM; i++)
        #pragma unroll
        for (int j = 0; j < FN; j++)
          acc[i][j] = __builtin_amdgcn_mfma_f32_16x16x32_bf16(af[i], bfr[j], acc[i][j], 0, 0, 0);
    }
  }

  float bv[FN];
  #pragma unroll
  for (int j = 0; j < FN; j++) bv[j] = bias[Nbase + (wn * FN + j) * 16 + l15];
  const int ncol = Nbase + wn * FN * 16 + l15;
  #pragma unroll
  for (int i = 0; i < FM; i++){
    #pragma unroll
    for (int r = 0; r < 4; r++){
      int p  = Mbase + (wm * FM + i) * 16 + quad * 4 + r;
      int b  = p / (HO * WO);
      int rr = p & (HO * WO - 1);
      int oh = rr / WO, ow = rr & (WO - 1);
      u16* op = out + (((size_t)b * HOP + oh + OPAD) * WOP + ow + OPAD) * CO + ncol;
      #pragma unroll
      for (int j = 0; j < FN; j++)
        op[j * 16] = f2bf(fmaxf(acc[i][j][r] + bv[j], 0.f));
    }
  }
}

// ---------------- pool ----------------
__global__ __launch_bounds__(512) void pool_k(const u16* __restrict__ act4,
                                              float* __restrict__ pooled){
  const int c = threadIdx.x;
  const int b = blockIdx.x;
  const u16* p = act4 + (size_t)b * 256 * 512 + c;
  float s = 0.f;
  for (int i = 0; i < 256; i++) s += bf2f(p[i * 512]);
  pooled[b * 512 + c] = s * (1.f / 256.f);
}

// ---------------- FC head ----------------
__global__ __launch_bounds__(64) void feat_k(const float* __restrict__ pooled,
                                             const float* __restrict__ hist,
                                             const float* __restrict__ wf, const float* __restrict__ bfv,
                                             const float* __restrict__ wh, const float* __restrict__ bh,
                                             const float* __restrict__ wo, const float* __restrict__ bo,
                                             float* __restrict__ cfeat){
  __shared__ float comb[128];
  const int j = threadIdx.x;
  const int b = blockIdx.x;
  const float* pb  = pooled + b * 512;
  const float* wfj = wf + j * 512;
  float s = bfv[j];
  for (int k = 0; k < 512; k++) s += pb[k] * wfj[k];
  comb[j] = s;
  const float* hb  = hist + b * 48;
  const float* whj = wh + j * 48;
  float t = bh[j];
  for (int k = 0; k < 48; k++) t += hb[k] * whj[k];
  comb[64 + j] = t;
  __syncthreads();
  if (j < 3){
    float c = bo[j];
    const float* woj = wo + j * 128;
    for (int k = 0; k < 128; k++) c += comb[k] * woj[k];
    cfeat[b * 3 + j] = c;
  }
}

// ---------------- broadcast ----------------
__global__ __launch_bounds__(256) void bcast_k(const float* __restrict__ cfeat,
                                               float* __restrict__ out){
  size_t i = (size_t)blockIdx.x * 256 + threadIdx.x;
  int bc = (int)(i >> 14);
  float v = cfeat[bc];
  ((float4*)out)[i] = make_float4(v, v, v, v);
}

extern "C" void kernel_launch(void* const* d_in, const int* in_sizes, int n_in,
                              void* d_out, int out_size, void* d_ws, size_t ws_size,
                              hipStream_t stream){
  const float* img = (const float*)d_in[0];
  const float* w1  = (const float*)d_in[1];
  const float* b1  = (const float*)d_in[2];
  const float* w2  = (const float*)d_in[3];
  const float* b2  = (const float*)d_in[4];
  const float* w3  = (const float*)d_in[5];
  const float* b3  = (const float*)d_in[6];
  const float* w4  = (const float*)d_in[7];
  const float* b4  = (const float*)d_in[8];
  const float* wf  = (const float*)d_in[9];
  const float* bfv = (const float*)d_in[10];
  const float* wh  = (const float*)d_in[11];
  const float* bh  = (const float*)d_in[12];
  const float* wo  = (const float*)d_in[13];
  const float* bo  = (const float*)d_in[14];
  float* out = (float*)d_out;
  (void)in_sizes; (void)n_in; (void)out_size; (void)ws_size;

  char* ws = (char*)d_ws;
  size_t off = 0;
  auto alloc = [&](size_t bytes) -> void* {
    void* p = ws + off;
    off += (bytes + 255) & ~(size_t)255;
    return p;
  };
  // Footprint ~75MB (<= proven 81MB). slot: act1c/act3c alias; imgr aliases act2c.
  constexpr int BC = 16;
  const size_t A1c  = (size_t)BC * 130 * 130 * 64 * 2;    // 34.6 MB
  const size_t A2c  = (size_t)BC * 66 * 66 * 128 * 2;     // 17.8 MB
  const size_t A3c  = (size_t)BC * 34 * 34 * 256 * 2;     //  9.5 MB (aliases slot)
  const size_t A4   = (size_t)64 * 16 * 16 * 512 * 2;     // 16.8 MB
  const size_t IMGR = (size_t)BC * 258 * 258 * 4 * 2;     //  8.5 MB (aliases act2c)

  u16*   slot = (u16*)alloc(A1c);
  u16*   act2 = (u16*)alloc(A2c);
  u16*   imgr = act2;                                     // alias, killed by act2 memset
  u16*   act4 = (u16*)alloc(A4);
  u16*   w1m  = (u16*)  alloc((size_t)64 * 64 * 2);
  u16*   w2r  = (u16*)  alloc((size_t)16 * 128 * 64 * 2);
  u16*   w3r  = (u16*)  alloc((size_t)16 * 256 * 128 * 2);
  u16*   w4r  = (u16*)  alloc((size_t)16 * 512 * 256 * 2);
  float* hist   = (float*)alloc((size_t)64 * 48 * 4);
  float* pooled = (float*)alloc((size_t)64 * 512 * 4);
  float* cfeat  = (float*)alloc((size_t)64 * 3 * 4);

  repack_w1m <<<dim3(16),   256, 0, stream>>>(w1, w1m);
  repack_w_bf<<<dim3(512),  256, 0, stream>>>(w2, w2r, 64, 128);
  repack_w_bf<<<dim3(2048), 256, 0, stream>>>(w3, w3r, 128, 256);
  repack_w_bf<<<dim3(8192), 256, 0, stream>>>(w4, w4r, 256, 512);

  hist_k<<<dim3(192), 256, 0, stream>>>(img, hist);

  for (int c = 0; c < 4; ++c){
    const float* img_c  = img  + (size_t)c * BC * 3 * 65536;
    u16*         act4_c = act4 + (size_t)c * BC * 256 * 512;

    hipMemsetAsync(imgr, 0, IMGR, stream);                // halo ring + prev act2 data
    repack_img<<<dim3(4096), 256, 0, stream>>>(img_c, imgr);
    hipMemsetAsync(slot, 0, A1c, stream);                 // act1c halo
    // conv1: M=262144, N=64 -> grid(1024,1), TM=256,TN=64
    conv1_mfma<<<dim3(1024), 256, 0, stream>>>(imgr, w1m, b1, slot);
    hipMemsetAsync(act2, 0, A2c, stream);                 // act2 halo (kills imgr)
    // conv2: 64->128, M=65536 -> 128x128 tiles, grid(512,1)
    conv_mfma<64, 128, 64, 64, 1, 2, 2, 4, 4>
        <<<dim3(512, 1), 256, 0, stream>>>(slot, w2r, b2, act2);
    hipMemsetAsync(slot, 0, A3c, stream);                 // act3c halo (aliases slot)
    // conv3: 128->256, M=16384 -> 64x128 tiles, grid(256,2)=512 blocks
    conv_mfma<128, 256, 32, 32, 1, 1, 4, 4, 2>
        <<<dim3(256, 2), 256, 0, stream>>>(act2, w3r, b3, slot);
    // conv4: 256->512, M=4096 -> 64x64 tiles, grid(64,8)=512 blocks
    conv_mfma<256, 512, 16, 16, 0, 2, 2, 2, 2>
        <<<dim3(64, 8), 256, 0, stream>>>(slot, w4r, b4, act4_c);
  }

  pool_k<<<dim3(64), 512, 0, stream>>>(act4, pooled);
  feat_k<<<dim3(64), 64, 0, stream>>>(pooled, hist, wf, bfv, wh, bh, wo, bo, cfeat);
  bcast_k<<<dim3(12288), 256, 0, stream>>>(cfeat, out);
}

// Round 6
// 1133.027 us; speedup vs baseline: 4.1250x; 1.0991x over previous
//
// Round 5: hist rewritten two-phase (1536 blocks, float4 loads, conflict-free
// transposed LDS counters, global atomicAdd partials) — was 124us @ 6.5% occ,
// 1.55M bank conflicts. Full-buffer memsets (~245MB/launch) replaced by
// halo-ring zero kernels (~4MB), sequenced around the slot/act2 aliases.
// conv1/2/3/4 MFMA kernels unchanged from round 4.
// Predicted: 1245 -> ~1000-1080us; top-5 becomes conv_mfma, MfmaUtil 20-40%.
#include <hip/hip_runtime.h>

typedef unsigned short u16;
typedef __attribute__((ext_vector_type(8))) short bf16x8;   // 8 bf16 (4 VGPRs)
typedef __attribute__((ext_vector_type(4))) float f32x4;

__device__ __forceinline__ float bf2f(u16 v){ return __uint_as_float(((unsigned)v) << 16); }
__device__ __forceinline__ u16 f2bf(float f){
  unsigned u = __float_as_uint(f);
  u += 0x7FFFu + ((u >> 16) & 1u);   // RNE
  return (u16)(u >> 16);
}

constexpr int ilog2c(int v){ return v <= 1 ? 0 : 1 + ilog2c(v / 2); }

// ---------------- weight repacks ----------------
// conv1: OIHW fp32 [64][3][4][4] -> [co][k=kh*16+kw*4+ci] bf16, ci padded to 4 (zeros)
__global__ __launch_bounds__(256) void repack_w1m(const float* __restrict__ src,
                                                  u16* __restrict__ dst){
  int i = blockIdx.x * 256 + threadIdx.x;     // over [64][64]
  if (i < 64 * 64){
    int k  = i & 63, co = i >> 6;
    int kh = k >> 4, kw = (k >> 2) & 3, ci = k & 3;
    float v = (ci < 3) ? src[((co * 3 + ci) * 4 + kh) * 4 + kw] : 0.f;
    dst[i] = f2bf(v);
  }
}
// conv2-4: OIHW fp32 -> [tap][co][ci] bf16 (B^T / [N][K] layout for MFMA)
__global__ __launch_bounds__(256) void repack_w_bf(const float* __restrict__ src,
                                                   u16* __restrict__ dst,
                                                   int CI, int CO){
  int i = blockIdx.x * 256 + threadIdx.x;     // linear over src = [co][ci][16]
  if (i < CO * CI * 16){
    int t  = i & 15;
    int r  = i >> 4;
    int ci = r & (CI - 1);
    int co = r / CI;
    dst[((size_t)t * CO + co) * CI + ci] = f2bf(src[i]);
  }
}

// ---------------- img repack: NCHW fp32 (16 imgs) -> [16][258][258][4] bf16 ----------------
__global__ __launch_bounds__(256) void repack_img(const float* __restrict__ img,
                                                  u16* __restrict__ dst){
  int i = blockIdx.x * 256 + threadIdx.x;     // over 16*65536 pixels
  int b  = i >> 16;
  int r  = i & 65535;
  int ih = r >> 8, iw = r & 255;
  float c0 = img[((size_t)b * 3 + 0) * 65536 + r];
  float c1 = img[((size_t)b * 3 + 1) * 65536 + r];
  float c2 = img[((size_t)b * 3 + 2) * 65536 + r];
  ushort4 v = { f2bf(c0), f2bf(c1), f2bf(c2), 0 };
  *(ushort4*)(dst + ((size_t)(b * 258 + ih + 1) * 258 + iw + 1) * 4) = v;
}

// ---------------- halo ring zero: [B][H][W][C] u16, C even ----------------
__global__ __launch_bounds__(256) void halo_zero(u16* __restrict__ buf,
                                                 int B, int H, int W, int C){
  const int C2 = C >> 1;                              // u32 cells per pixel
  const int rowCells = W * C2;                        // one full row
  const int colCells = (H - 2) * C2;                  // one side column
  const int perImg = 2 * rowCells + 2 * colCells;
  int i = blockIdx.x * 256 + threadIdx.x;
  if (i >= B * perImg) return;
  int b = i / perImg, r = i % perImg;
  int h, w, cx;
  if (r < 2 * rowCells){
    h = (r < rowCells) ? 0 : (H - 1);
    int rr = (r < rowCells) ? r : (r - rowCells);
    w = rr / C2; cx = rr % C2;
  } else {
    int rr = r - 2 * rowCells;
    int side = rr / colCells, r2 = rr % colCells;
    h = 1 + r2 / C2; w = side ? (W - 1) : 0; cx = r2 % C2;
  }
  ((unsigned*)buf)[(((size_t)b * H + h) * W + w) * C2 + cx] = 0u;
}

// ---------------- histogram phase 1: partial counts ----------------
// grid (192, 8): block (bc,s) counts pixels [s*8192, s*8192+8192) of plane bc.
// LDS counters transposed: cnt[idx*256+tid] -> bank = tid%32, conflict-free.
__global__ __launch_bounds__(256) void hist_part(const float* __restrict__ img,
                                                 float* __restrict__ raw){
  __shared__ float cnt[16 * 256];
  __shared__ float partial[16 * 17];
  const int tid = threadIdx.x;
  const int bc  = blockIdx.x;
  #pragma unroll
  for (int i = 0; i < 16; i++) cnt[i * 256 + tid] = 0.f;
  __syncthreads();
  const float4* p = (const float4*)(img + (size_t)bc * 65536 + blockIdx.y * 8192);
  #pragma unroll
  for (int it = 0; it < 8; ++it){
    float4 v = p[it * 256 + tid];
    float c[4] = { v.x, v.y, v.z, v.w };
    #pragma unroll
    for (int j = 0; j < 4; j++){
      float x = (c[j] + 1.f) * 0.5f;
      int idx = (int)floorf((x + 1.f) * 8.f);
      idx = min(max(idx, 0), 15);
      float inr = (x >= -1.f && x <= 1.f) ? 1.f : 0.f;
      cnt[idx * 256 + tid] += inr;
    }
  }
  __syncthreads();
  {
    int bin = tid & 15, g = tid >> 4;
    float s = 0.f;
    #pragma unroll
    for (int j = 0; j < 16; j++) s += cnt[bin * 256 + g * 16 + j];
    partial[bin * 17 + g] = s;
  }
  __syncthreads();
  if (tid < 16){
    float t = 0.f;
    #pragma unroll
    for (int g = 0; g < 16; g++) t += partial[tid * 17 + g];
    atomicAdd(raw + bc * 16 + tid, t);    // integer-valued floats: order-exact
  }
}

// ---------------- histogram phase 2: normalize ----------------
__global__ __launch_bounds__(256) void hist_finish(const float* __restrict__ raw,
                                                   float* __restrict__ hist){
  int i = blockIdx.x * 256 + threadIdx.x;   // over 192*16
  if (i < 3072){
    const float* r = raw + (i >> 4) * 16;
    float s = 0.f;
    #pragma unroll
    for (int j = 0; j < 16; j++) s += r[j];
    hist[i] = r[i & 15] / (s + 1e-6f);
  }
}

// ---------------- conv1 MFMA: imgr [16][258][258][4] -> act1 [16][130][130][64] ----------
__global__ __launch_bounds__(256, 2) void conv1_mfma(const u16* __restrict__ in,
                                                     const u16* __restrict__ wm1,  // [64][64]
                                                     const float* __restrict__ bias,
                                                     u16* __restrict__ out){
  __shared__ __align__(16) u16 ldsA[256 * 32];
  __shared__ __align__(16) u16 ldsB[64 * 32];
  const int tid  = threadIdx.x;
  const int lane = tid & 63;
  const int w    = tid >> 6;
  const int quad = lane >> 4, l15 = lane & 15;
  const int Mbase = blockIdx.x * 256;

  const int srow = tid >> 2;
  const int c    = tid & 3;
  int a0[4];
  #pragma unroll
  for (int i = 0; i < 4; i++){
    int p  = Mbase + srow + 64 * i;
    int b  = p >> 14;
    int rr = p & 16383;
    int oh = rr >> 7, ow = rr & 127;
    a0[i] = ((b * 258 + 2 * oh + (c >> 1)) * 258 + 2 * ow + (c & 1) * 2) * 4;
  }
  const int b0 = srow * 64 + c * 8;

  f32x4 acc[4][4];
  #pragma unroll
  for (int i = 0; i < 4; i++)
    #pragma unroll
    for (int j = 0; j < 4; j++) acc[i][j] = (f32x4){0.f, 0.f, 0.f, 0.f};

  #pragma unroll
  for (int cc = 0; cc < 2; ++cc){
    uint4 ra[4];
    #pragma unroll
    for (int i = 0; i < 4; i++) ra[i] = *(const uint4*)(in + a0[i] + cc * 2064);
    uint4 rb = *(const uint4*)(wm1 + b0 + cc * 32);
    __syncthreads();
    #pragma unroll
    for (int i = 0; i < 4; i++)
      *(uint4*)(ldsA + (srow + 64 * i) * 32 + c * 8) = ra[i];
    *(uint4*)(ldsB + srow * 32 + c * 8) = rb;
    __syncthreads();
    bf16x8 af[4], bfr[4];
    #pragma unroll
    for (int i = 0; i < 4; i++)
      af[i]  = *(const bf16x8*)(ldsA + (w * 64 + i * 16 + l15) * 32 + quad * 8);
    #pragma unroll
    for (int j = 0; j < 4; j++)
      bfr[j] = *(const bf16x8*)(ldsB + (j * 16 + l15) * 32 + quad * 8);
    #pragma unroll
    for (int i = 0; i < 4; i++)
      #pragma unroll
      for (int j = 0; j < 4; j++)
        acc[i][j] = __builtin_amdgcn_mfma_f32_16x16x32_bf16(af[i], bfr[j], acc[i][j], 0, 0, 0);
  }

  float bv[4];
  #pragma unroll
  for (int j = 0; j < 4; j++) bv[j] = bias[j * 16 + l15];
  #pragma unroll
  for (int i = 0; i < 4; i++){
    #pragma unroll
    for (int r = 0; r < 4; r++){
      int p  = Mbase + w * 64 + i * 16 + quad * 4 + r;
      int b  = p >> 14;
      int rr = p & 16383;
      int oh = rr >> 7, ow = rr & 127;
      u16* op = out + ((size_t)(b * 130 + oh + 1) * 130 + ow + 1) * 64 + l15;
      #pragma unroll
      for (int j = 0; j < 4; j++)
        op[j * 16] = f2bf(fmaxf(acc[i][j][r] + bv[j], 0.f));
    }
  }
}

// ---------------- generic MFMA implicit-GEMM stride-2 4x4 conv ----------------
template<int CI, int CO, int HO, int WO, int OPAD, int WM, int WN, int FM, int FN>
__global__ __launch_bounds__(256, 2) void conv_mfma(const u16* __restrict__ in,
                                                    const u16* __restrict__ wr,
                                                    const float* __restrict__ bias,
                                                    u16* __restrict__ out){
  constexpr int HI  = 2 * HO + 2, WI = 2 * WO + 2;
  constexpr int HOP = HO + 2 * OPAD, WOP = WO + 2 * OPAD;
  constexpr int CC  = CI / 32;
  constexpr int TM  = WM * FM * 16, TN = WN * FN * 16;
  constexpr int ACH = TM / 64, BCH = TN / 64;
  __shared__ __align__(16) u16 ldsA[TM * 32];
  __shared__ __align__(16) u16 ldsB[TN * 32];
  const int tid  = threadIdx.x;
  const int lane = tid & 63;
  const int w    = tid >> 6;
  const int quad = lane >> 4, l15 = lane & 15;
  const int wm = w & (WM - 1), wn = w >> ilog2c(WM);
  const int Mbase = blockIdx.x * TM;
  const int Nbase = blockIdx.y * TN;

  const int srow = tid >> 2;
  const int sel  = (tid & 3) * 8;
  int apix[ACH], brow[BCH];
  #pragma unroll
  for (int i = 0; i < ACH; i++){
    int p  = Mbase + srow + 64 * i;
    int b  = p / (HO * WO);
    int r  = p & (HO * WO - 1);
    int oh = r / WO, ow = r & (WO - 1);
    apix[i] = ((b * HI + 2 * oh) * WI + 2 * ow) * CI + sel;
  }
  #pragma unroll
  for (int i = 0; i < BCH; i++)
    brow[i] = (Nbase + srow + 64 * i) * CI + sel;

  f32x4 acc[FM][FN];
  #pragma unroll
  for (int i = 0; i < FM; i++)
    #pragma unroll
    for (int j = 0; j < FN; j++) acc[i][j] = (f32x4){0.f, 0.f, 0.f, 0.f};

  #pragma unroll 1
  for (int tap = 0; tap < 16; ++tap){
    const int kh = tap >> 2, kw = tap & 3;
    const int ad = (kh * WI + kw) * CI;
    const int bd = tap * CO * CI;
    #pragma unroll 1
    for (int cc = 0; cc < CC; ++cc){
      const int ci0 = cc * 32;
      uint4 ra[ACH], rb[BCH];
      #pragma unroll
      for (int i = 0; i < ACH; i++) ra[i] = *(const uint4*)(in + apix[i] + ad + ci0);
      #pragma unroll
      for (int i = 0; i < BCH; i++) rb[i] = *(const uint4*)(wr + brow[i] + bd + ci0);
      __syncthreads();
      #pragma unroll
      for (int i = 0; i < ACH; i++)
        *(uint4*)(ldsA + (srow + 64 * i) * 32 + sel) = ra[i];
      #pragma unroll
      for (int i = 0; i < BCH; i++)
        *(uint4*)(ldsB + (srow + 64 * i) * 32 + sel) = rb[i];
      __syncthreads();
      bf16x8 af[FM], bfr[FN];
      #pragma unroll
      for (int i = 0; i < FM; i++)
        af[i]  = *(const bf16x8*)(ldsA + ((wm * FM + i) * 16 + l15) * 32 + quad * 8);
      #pragma unroll
      for (int j = 0; j < FN; j++)
        bfr[j] = *(const bf16x8*)(ldsB + ((wn * FN + j) * 16 + l15) * 32 + quad * 8);
      #pragma unroll
      for (int i = 0; i < FM; i++)
        #pragma unroll
        for (int j = 0; j < FN; j++)
          acc[i][j] = __builtin_amdgcn_mfma_f32_16x16x32_bf16(af[i], bfr[j], acc[i][j], 0, 0, 0);
    }
  }

  float bv[FN];
  #pragma unroll
  for (int j = 0; j < FN; j++) bv[j] = bias[Nbase + (wn * FN + j) * 16 + l15];
  const int ncol = Nbase + wn * FN * 16 + l15;
  #pragma unroll
  for (int i = 0; i < FM; i++){
    #pragma unroll
    for (int r = 0; r < 4; r++){
      int p  = Mbase + (wm * FM + i) * 16 + quad * 4 + r;
      int b  = p / (HO * WO);
      int rr = p & (HO * WO - 1);
      int oh = rr / WO, ow = rr & (WO - 1);
      u16* op = out + (((size_t)b * HOP + oh + OPAD) * WOP + ow + OPAD) * CO + ncol;
      #pragma unroll
      for (int j = 0; j < FN; j++)
        op[j * 16] = f2bf(fmaxf(acc[i][j][r] + bv[j], 0.f));
    }
  }
}

// ---------------- pool ----------------
__global__ __launch_bounds__(512) void pool_k(const u16* __restrict__ act4,
                                              float* __restrict__ pooled){
  const int c = threadIdx.x;
  const int b = blockIdx.x;
  const u16* p = act4 + (size_t)b * 256 * 512 + c;
  float s = 0.f;
  for (int i = 0; i < 256; i++) s += bf2f(p[i * 512]);
  pooled[b * 512 + c] = s * (1.f / 256.f);
}

// ---------------- FC head ----------------
__global__ __launch_bounds__(64) void feat_k(const float* __restrict__ pooled,
                                             const float* __restrict__ hist,
                                             const float* __restrict__ wf, const float* __restrict__ bfv,
                                             const float* __restrict__ wh, const float* __restrict__ bh,
                                             const float* __restrict__ wo, const float* __restrict__ bo,
                                             float* __restrict__ cfeat){
  __shared__ float comb[128];
  const int j = threadIdx.x;
  const int b = blockIdx.x;
  const float* pb  = pooled + b * 512;
  const float* wfj = wf + j * 512;
  float s = bfv[j];
  for (int k = 0; k < 512; k++) s += pb[k] * wfj[k];
  comb[j] = s;
  const float* hb  = hist + b * 48;
  const float* whj = wh + j * 48;
  float t = bh[j];
  for (int k = 0; k < 48; k++) t += hb[k] * whj[k];
  comb[64 + j] = t;
  __syncthreads();
  if (j < 3){
    float c = bo[j];
    const float* woj = wo + j * 128;
    for (int k = 0; k < 128; k++) c += comb[k] * woj[k];
    cfeat[b * 3 + j] = c;
  }
}

// ---------------- broadcast ----------------
__global__ __launch_bounds__(256) void bcast_k(const float* __restrict__ cfeat,
                                               float* __restrict__ out){
  size_t i = (size_t)blockIdx.x * 256 + threadIdx.x;
  int bc = (int)(i >> 14);
  float v = cfeat[bc];
  ((float4*)out)[i] = make_float4(v, v, v, v);
}

extern "C" void kernel_launch(void* const* d_in, const int* in_sizes, int n_in,
                              void* d_out, int out_size, void* d_ws, size_t ws_size,
                              hipStream_t stream){
  const float* img = (const float*)d_in[0];
  const float* w1  = (const float*)d_in[1];
  const float* b1  = (const float*)d_in[2];
  const float* w2  = (const float*)d_in[3];
  const float* b2  = (const float*)d_in[4];
  const float* w3  = (const float*)d_in[5];
  const float* b3  = (const float*)d_in[6];
  const float* w4  = (const float*)d_in[7];
  const float* b4  = (const float*)d_in[8];
  const float* wf  = (const float*)d_in[9];
  const float* bfv = (const float*)d_in[10];
  const float* wh  = (const float*)d_in[11];
  const float* bh  = (const float*)d_in[12];
  const float* wo  = (const float*)d_in[13];
  const float* bo  = (const float*)d_in[14];
  float* out = (float*)d_out;
  (void)in_sizes; (void)n_in; (void)out_size; (void)ws_size;

  char* ws = (char*)d_ws;
  size_t off = 0;
  auto alloc = [&](size_t bytes) -> void* {
    void* p = ws + off;
    off += (bytes + 255) & ~(size_t)255;
    return p;
  };
  // ~75MB proven layout: slot = act1c/act3c alias; imgr aliases act2c start.
  constexpr int BC = 16;
  const size_t A1c  = (size_t)BC * 130 * 130 * 64 * 2;    // 34.6 MB
  const size_t A2c  = (size_t)BC * 66 * 66 * 128 * 2;     // 17.8 MB
  const size_t A4   = (size_t)64 * 16 * 16 * 512 * 2;     // 16.8 MB

  u16*   slot = (u16*)alloc(A1c);
  u16*   act2 = (u16*)alloc(A2c);
  u16*   imgr = act2;                                     // alias
  u16*   act4 = (u16*)alloc(A4);
  u16*   w1m  = (u16*)  alloc((size_t)64 * 64 * 2);
  u16*   w2r  = (u16*)  alloc((size_t)16 * 128 * 64 * 2);
  u16*   w3r  = (u16*)  alloc((size_t)16 * 256 * 128 * 2);
  u16*   w4r  = (u16*)  alloc((size_t)16 * 512 * 256 * 2);
  float* raw    = (float*)alloc((size_t)192 * 16 * 4);
  float* hist   = (float*)alloc((size_t)192 * 16 * 4);
  float* pooled = (float*)alloc((size_t)64 * 512 * 4);
  float* cfeat  = (float*)alloc((size_t)64 * 3 * 4);

  repack_w1m <<<dim3(16),   256, 0, stream>>>(w1, w1m);
  repack_w_bf<<<dim3(512),  256, 0, stream>>>(w2, w2r, 64, 128);
  repack_w_bf<<<dim3(2048), 256, 0, stream>>>(w3, w3r, 128, 256);
  repack_w_bf<<<dim3(8192), 256, 0, stream>>>(w4, w4r, 256, 512);

  hipMemsetAsync(raw, 0, 192 * 16 * 4, stream);
  hist_part<<<dim3(192, 8), 256, 0, stream>>>(img, raw);
  hist_finish<<<dim3(12), 256, 0, stream>>>(raw, hist);

  // halo u32 cell counts
  const int nH1 = 16 * (2 * 130 * 32 + 128 * 2 * 32);   // act1  [16][130][130][64]
  const int nH2 = 16 * (2 * 66 * 64 + 64 * 2 * 64);     // act2  [16][66][66][128]
  const int nH3 = 16 * (2 * 34 * 128 + 32 * 2 * 128);   // act3  [16][34][34][256]
  const int nHI = 16 * (2 * 258 * 2 + 256 * 2 * 2);     // imgr  [16][258][258][4]

  for (int c = 0; c < 4; ++c){
    const float* img_c  = img  + (size_t)c * BC * 3 * 65536;
    u16*         act4_c = act4 + (size_t)c * BC * 256 * 512;

    halo_zero<<<dim3((nHI + 255) / 256), 256, 0, stream>>>(imgr, 16, 258, 258, 4);
    repack_img<<<dim3(4096), 256, 0, stream>>>(img_c, imgr);
    halo_zero<<<dim3((nH1 + 255) / 256), 256, 0, stream>>>(slot, 16, 130, 130, 64);
    conv1_mfma<<<dim3(1024), 256, 0, stream>>>(imgr, w1m, b1, slot);
    halo_zero<<<dim3((nH2 + 255) / 256), 256, 0, stream>>>(act2, 16, 66, 66, 128);  // imgr dead
    conv_mfma<64, 128, 64, 64, 1, 2, 2, 4, 4>
        <<<dim3(512, 1), 256, 0, stream>>>(slot, w2r, b2, act2);
    halo_zero<<<dim3((nH3 + 255) / 256), 256, 0, stream>>>(slot, 16, 34, 34, 256);  // act1 dead
    conv_mfma<128, 256, 32, 32, 1, 1, 4, 4, 2>
        <<<dim3(256, 2), 256, 0, stream>>>(act2, w3r, b3, slot);
    conv_mfma<256, 512, 16, 16, 0, 2, 2, 2, 2>
        <<<dim3(64, 8), 256, 0, stream>>>(slot, w4r, b4, act4_c);
  }

  pool_k<<<dim3(64), 512, 0, stream>>>(act4, pooled);
  feat_k<<<dim3(64), 64, 0, stream>>>(pooled, hist, wf, bfv, wh, bh, wo, bo, cfeat);
  bcast_k<<<dim3(12288), 256, 0, stream>>>(cfeat, out);
}

// Round 7
// 919.466 us; speedup vs baseline: 5.0831x; 1.2323x over previous
//
// Round 6: conv epilogues rewritten (acc -> LDS -> coalesced uint4 stores; was
// 64 scattered 2B stores/thread -> WRITE_SIZE 101MB vs 17.8MB actual = 6x HBM
// write amplification), register prefetch of next K-slab (overlaps L2 latency
// with ds_read+MFMA instead of exposing it per-iter), conv2 retiled TM=64 ->
// 1024 blocks (4/CU). Memory plan unchanged (~75MB proven).
// Predicted: 1133 -> ~770-850us; conv2 87->~40us, WRITE ~20MB, MfmaUtil ~15%.
#include <hip/hip_runtime.h>

typedef unsigned short u16;
typedef __attribute__((ext_vector_type(8))) short bf16x8;   // 8 bf16 (4 VGPRs)
typedef __attribute__((ext_vector_type(4))) float f32x4;

__device__ __forceinline__ float bf2f(u16 v){ return __uint_as_float(((unsigned)v) << 16); }
__device__ __forceinline__ u16 f2bf(float f){
  unsigned u = __float_as_uint(f);
  u += 0x7FFFu + ((u >> 16) & 1u);   // RNE
  return (u16)(u >> 16);
}

constexpr int ilog2c(int v){ return v <= 1 ? 0 : 1 + ilog2c(v / 2); }

// ---------------- weight repacks ----------------
__global__ __launch_bounds__(256) void repack_w1m(const float* __restrict__ src,
                                                  u16* __restrict__ dst){
  int i = blockIdx.x * 256 + threadIdx.x;     // over [64][64]
  if (i < 64 * 64){
    int k  = i & 63, co = i >> 6;
    int kh = k >> 4, kw = (k >> 2) & 3, ci = k & 3;
    float v = (ci < 3) ? src[((co * 3 + ci) * 4 + kh) * 4 + kw] : 0.f;
    dst[i] = f2bf(v);
  }
}
__global__ __launch_bounds__(256) void repack_w_bf(const float* __restrict__ src,
                                                   u16* __restrict__ dst,
                                                   int CI, int CO){
  int i = blockIdx.x * 256 + threadIdx.x;     // linear over src = [co][ci][16]
  if (i < CO * CI * 16){
    int t  = i & 15;
    int r  = i >> 4;
    int ci = r & (CI - 1);
    int co = r / CI;
    dst[((size_t)t * CO + co) * CI + ci] = f2bf(src[i]);
  }
}

// ---------------- img repack: NCHW fp32 (16 imgs) -> [16][258][258][4] bf16 ----------------
__global__ __launch_bounds__(256) void repack_img(const float* __restrict__ img,
                                                  u16* __restrict__ dst){
  int i = blockIdx.x * 256 + threadIdx.x;
  int b  = i >> 16;
  int r  = i & 65535;
  int ih = r >> 8, iw = r & 255;
  float c0 = img[((size_t)b * 3 + 0) * 65536 + r];
  float c1 = img[((size_t)b * 3 + 1) * 65536 + r];
  float c2 = img[((size_t)b * 3 + 2) * 65536 + r];
  ushort4 v = { f2bf(c0), f2bf(c1), f2bf(c2), 0 };
  *(ushort4*)(dst + ((size_t)(b * 258 + ih + 1) * 258 + iw + 1) * 4) = v;
}

// ---------------- halo ring zero ----------------
__global__ __launch_bounds__(256) void halo_zero(u16* __restrict__ buf,
                                                 int B, int H, int W, int C){
  const int C2 = C >> 1;
  const int rowCells = W * C2;
  const int colCells = (H - 2) * C2;
  const int perImg = 2 * rowCells + 2 * colCells;
  int i = blockIdx.x * 256 + threadIdx.x;
  if (i >= B * perImg) return;
  int b = i / perImg, r = i % perImg;
  int h, w, cx;
  if (r < 2 * rowCells){
    h = (r < rowCells) ? 0 : (H - 1);
    int rr = (r < rowCells) ? r : (r - rowCells);
    w = rr / C2; cx = rr % C2;
  } else {
    int rr = r - 2 * rowCells;
    int side = rr / colCells, r2 = rr % colCells;
    h = 1 + r2 / C2; w = side ? (W - 1) : 0; cx = r2 % C2;
  }
  ((unsigned*)buf)[(((size_t)b * H + h) * W + w) * C2 + cx] = 0u;
}

// ---------------- histogram ----------------
__global__ __launch_bounds__(256) void hist_part(const float* __restrict__ img,
                                                 float* __restrict__ raw){
  __shared__ float cnt[16 * 256];
  __shared__ float partial[16 * 17];
  const int tid = threadIdx.x;
  const int bc  = blockIdx.x;
  #pragma unroll
  for (int i = 0; i < 16; i++) cnt[i * 256 + tid] = 0.f;
  __syncthreads();
  const float4* p = (const float4*)(img + (size_t)bc * 65536 + blockIdx.y * 8192);
  #pragma unroll
  for (int it = 0; it < 8; ++it){
    float4 v = p[it * 256 + tid];
    float c[4] = { v.x, v.y, v.z, v.w };
    #pragma unroll
    for (int j = 0; j < 4; j++){
      float x = (c[j] + 1.f) * 0.5f;
      int idx = (int)floorf((x + 1.f) * 8.f);
      idx = min(max(idx, 0), 15);
      float inr = (x >= -1.f && x <= 1.f) ? 1.f : 0.f;
      cnt[idx * 256 + tid] += inr;
    }
  }
  __syncthreads();
  {
    int bin = tid & 15, g = tid >> 4;
    float s = 0.f;
    #pragma unroll
    for (int j = 0; j < 16; j++) s += cnt[bin * 256 + g * 16 + j];
    partial[bin * 17 + g] = s;
  }
  __syncthreads();
  if (tid < 16){
    float t = 0.f;
    #pragma unroll
    for (int g = 0; g < 16; g++) t += partial[tid * 17 + g];
    atomicAdd(raw + bc * 16 + tid, t);
  }
}
__global__ __launch_bounds__(256) void hist_finish(const float* __restrict__ raw,
                                                   float* __restrict__ hist){
  int i = blockIdx.x * 256 + threadIdx.x;
  if (i < 3072){
    const float* r = raw + (i >> 4) * 16;
    float s = 0.f;
    #pragma unroll
    for (int j = 0; j < 16; j++) s += r[j];
    hist[i] = r[i & 15] / (s + 1e-6f);
  }
}

// ---------------- conv1 MFMA: imgr [16][258][258][4] -> act1 [16][130][130][64] ----------
// GEMM M=262144,N=64,K=64. Prefetched slabs; LDS-staged coalesced epilogue.
__global__ __launch_bounds__(256, 2) void conv1_mfma(const u16* __restrict__ in,
                                                     const u16* __restrict__ wm1,  // [64][64]
                                                     const float* __restrict__ bias,
                                                     u16* __restrict__ out){
  __shared__ __align__(16) u16 lds[256 * 32 + 64 * 32];
  u16* ldsA = lds;
  u16* ldsB = lds + 256 * 32;
  const int tid  = threadIdx.x;
  const int lane = tid & 63;
  const int w    = tid >> 6;
  const int quad = lane >> 4, l15 = lane & 15;
  const int Mbase = blockIdx.x * 256;

  const int srow = tid >> 2;
  const int c    = tid & 3;
  int a0[4];
  #pragma unroll
  for (int i = 0; i < 4; i++){
    int p  = Mbase + srow + 64 * i;
    int b  = p >> 14;
    int rr = p & 16383;
    int oh = rr >> 7, ow = rr & 127;
    a0[i] = ((b * 258 + 2 * oh + (c >> 1)) * 258 + 2 * ow + (c & 1) * 2) * 4;
  }
  const int b0 = srow * 64 + c * 8;

  f32x4 acc[4][4];
  #pragma unroll
  for (int i = 0; i < 4; i++)
    #pragma unroll
    for (int j = 0; j < 4; j++) acc[i][j] = (f32x4){0.f, 0.f, 0.f, 0.f};

  uint4 ra[4], rb1;
  #pragma unroll
  for (int i = 0; i < 4; i++) ra[i] = *(const uint4*)(in + a0[i]);
  rb1 = *(const uint4*)(wm1 + b0);

  #pragma unroll
  for (int cc = 0; cc < 2; ++cc){
    __syncthreads();
    #pragma unroll
    for (int i = 0; i < 4; i++)
      *(uint4*)(ldsA + (srow + 64 * i) * 32 + c * 8) = ra[i];
    *(uint4*)(ldsB + srow * 32 + c * 8) = rb1;
    __syncthreads();
    if (cc == 0){
      #pragma unroll
      for (int i = 0; i < 4; i++) ra[i] = *(const uint4*)(in + a0[i] + 2064);
      rb1 = *(const uint4*)(wm1 + b0 + 32);
    }
    bf16x8 af[4], bfr[4];
    #pragma unroll
    for (int i = 0; i < 4; i++)
      af[i]  = *(const bf16x8*)(ldsA + (w * 64 + i * 16 + l15) * 32 + quad * 8);
    #pragma unroll
    for (int j = 0; j < 4; j++)
      bfr[j] = *(const bf16x8*)(ldsB + (j * 16 + l15) * 32 + quad * 8);
    #pragma unroll
    for (int i = 0; i < 4; i++)
      #pragma unroll
      for (int j = 0; j < 4; j++)
        acc[i][j] = __builtin_amdgcn_mfma_f32_16x16x32_bf16(af[i], bfr[j], acc[i][j], 0, 0, 0);
  }

  // epilogue: 8 passes x 32 pixels; LDS row stride 72 u16 (pad +8)
  float bv[4];
  #pragma unroll
  for (int j = 0; j < 4; j++) bv[j] = bias[j * 16 + l15];
  const int tpp = tid & 7, pp = tid >> 3;
  #pragma unroll 1
  for (int ps = 0; ps < 8; ++ps){
    __syncthreads();
    #pragma unroll
    for (int i = 0; i < 4; i++){
      const int fr = w * 4 + i;
      if ((fr >> 1) == ps){
        const int lr0 = (fr & 1) * 16 + quad * 4;
        #pragma unroll
        for (int r = 0; r < 4; r++)
          #pragma unroll
          for (int j = 0; j < 4; j++)
            lds[(lr0 + r) * 72 + j * 16 + l15] = f2bf(fmaxf(acc[i][j][r] + bv[j], 0.f));
      }
    }
    __syncthreads();
    int gp = Mbase + ps * 32 + pp;
    int b  = gp >> 14;
    int rr = gp & 16383;
    int oh = rr >> 7, ow = rr & 127;
    u16* op = out + ((size_t)(b * 130 + oh + 1) * 130 + ow + 1) * 64 + tpp * 8;
    *(uint4*)op = *(const uint4*)(lds + pp * 72 + tpp * 8);
  }
}

// ---------------- generic MFMA implicit-GEMM stride-2 4x4 conv ----------------
// Prefetched K-slabs; LDS-staged coalesced epilogue (32-pixel passes).
template<int CI, int CO, int HO, int WO, int OPAD, int WM, int WN, int FM, int FN>
__global__ __launch_bounds__(256, 2) void conv_mfma(const u16* __restrict__ in,
                                                    const u16* __restrict__ wr,
                                                    const float* __restrict__ bias,
                                                    u16* __restrict__ out){
  constexpr int HI  = 2 * HO + 2, WI = 2 * WO + 2;
  constexpr int HOP = HO + 2 * OPAD, WOP = WO + 2 * OPAD;
  constexpr int CC  = CI / 32;
  constexpr int LCC = ilog2c(CC);
  constexpr int NIT = 16 * CC;
  constexpr int TM  = WM * FM * 16, TN = WN * FN * 16;
  constexpr int ACH = TM / 64, BCH = TN / 64;
  constexpr int EPS = TN + 8;                 // epilogue LDS row stride (u16)
  constexpr int U4  = TN / 64;                // uint4 per thread per pass
  __shared__ __align__(16) u16 lds[(TM + TN) * 32];
  u16* ldsA = lds;
  u16* ldsB = lds + TM * 32;
  const int tid  = threadIdx.x;
  const int lane = tid & 63;
  const int w    = tid >> 6;
  const int quad = lane >> 4, l15 = lane & 15;
  const int wm = w & (WM - 1), wn = w >> ilog2c(WM);
  const int Mbase = blockIdx.x * TM;
  const int Nbase = blockIdx.y * TN;

  const int srow = tid >> 2;
  const int sel  = (tid & 3) * 8;
  int apix[ACH], brow[BCH];
  #pragma unroll
  for (int i = 0; i < ACH; i++){
    int p  = Mbase + srow + 64 * i;
    int b  = p / (HO * WO);
    int r  = p & (HO * WO - 1);
    int oh = r / WO, ow = r & (WO - 1);
    apix[i] = ((b * HI + 2 * oh) * WI + 2 * ow) * CI + sel;
  }
  #pragma unroll
  for (int i = 0; i < BCH; i++)
    brow[i] = (Nbase + srow + 64 * i) * CI + sel;

  f32x4 acc[FM][FN];
  #pragma unroll
  for (int i = 0; i < FM; i++)
    #pragma unroll
    for (int j = 0; j < FN; j++) acc[i][j] = (f32x4){0.f, 0.f, 0.f, 0.f};

  uint4 ra[ACH], rb[BCH];
  auto fetch = [&](int it){
    const int tap = it >> LCC, cc = it & (CC - 1);
    const int ad = ((tap >> 2) * WI + (tap & 3)) * CI + cc * 32;
    const int bd = tap * CO * CI + cc * 32;
    #pragma unroll
    for (int i = 0; i < ACH; i++) ra[i] = *(const uint4*)(in + apix[i] + ad);
    #pragma unroll
    for (int i = 0; i < BCH; i++) rb[i] = *(const uint4*)(wr + brow[i] + bd);
  };
  fetch(0);

  #pragma unroll 1
  for (int it = 0; it < NIT; ++it){
    __syncthreads();
    #pragma unroll
    for (int i = 0; i < ACH; i++)
      *(uint4*)(ldsA + (srow + 64 * i) * 32 + sel) = ra[i];
    #pragma unroll
    for (int i = 0; i < BCH; i++)
      *(uint4*)(ldsB + (srow + 64 * i) * 32 + sel) = rb[i];
    __syncthreads();
    if (it + 1 < NIT) fetch(it + 1);          // overlaps ds_read + MFMA below
    bf16x8 af[FM], bfr[FN];
    #pragma unroll
    for (int i = 0; i < FM; i++)
      af[i]  = *(const bf16x8*)(ldsA + ((wm * FM + i) * 16 + l15) * 32 + quad * 8);
    #pragma unroll
    for (int j = 0; j < FN; j++)
      bfr[j] = *(const bf16x8*)(ldsB + ((wn * FN + j) * 16 + l15) * 32 + quad * 8);
    #pragma unroll
    for (int i = 0; i < FM; i++)
      #pragma unroll
      for (int j = 0; j < FN; j++)
        acc[i][j] = __builtin_amdgcn_mfma_f32_16x16x32_bf16(af[i], bfr[j], acc[i][j], 0, 0, 0);
  }

  // epilogue: TM/32 passes of 32 pixels through LDS, coalesced uint4 stores
  float bv[FN];
  #pragma unroll
  for (int j = 0; j < FN; j++) bv[j] = bias[Nbase + (wn * FN + j) * 16 + l15];
  const int tpp = tid & 7, pp = tid >> 3;
  #pragma unroll 1
  for (int ps = 0; ps < TM / 32; ++ps){
    __syncthreads();
    #pragma unroll
    for (int i = 0; i < FM; i++){
      const int fr = wm * FM + i;
      if ((fr >> 1) == ps){
        const int lr0 = (fr & 1) * 16 + quad * 4;
        #pragma unroll
        for (int r = 0; r < 4; r++)
          #pragma unroll
          for (int j = 0; j < FN; j++)
            lds[(lr0 + r) * EPS + (wn * FN + j) * 16 + l15] =
                f2bf(fmaxf(acc[i][j][r] + bv[j], 0.f));
      }
    }
    __syncthreads();
    int gp = Mbase + ps * 32 + pp;
    int b  = gp / (HO * WO);
    int rr = gp & (HO * WO - 1);
    int oh = rr / WO, ow = rr & (WO - 1);
    u16* op = out + (((size_t)b * HOP + oh + OPAD) * WOP + ow + OPAD) * CO
                  + Nbase + tpp * (TN / 8);
    #pragma unroll
    for (int u = 0; u < U4; u++)
      *(uint4*)(op + u * 8) = *(const uint4*)(lds + pp * EPS + tpp * (TN / 8) + u * 8);
  }
}

// ---------------- pool ----------------
__global__ __launch_bounds__(512) void pool_k(const u16* __restrict__ act4,
                                              float* __restrict__ pooled){
  const int c = threadIdx.x;
  const int b = blockIdx.x;
  const u16* p = act4 + (size_t)b * 256 * 512 + c;
  float s = 0.f;
  for (int i = 0; i < 256; i++) s += bf2f(p[i * 512]);
  pooled[b * 512 + c] = s * (1.f / 256.f);
}

// ---------------- FC head ----------------
__global__ __launch_bounds__(64) void feat_k(const float* __restrict__ pooled,
                                             const float* __restrict__ hist,
                                             const float* __restrict__ wf, const float* __restrict__ bfv,
                                             const float* __restrict__ wh, const float* __restrict__ bh,
                                             const float* __restrict__ wo, const float* __restrict__ bo,
                                             float* __restrict__ cfeat){
  __shared__ float comb[128];
  const int j = threadIdx.x;
  const int b = blockIdx.x;
  const float* pb  = pooled + b * 512;
  const float* wfj = wf + j * 512;
  float s = bfv[j];
  for (int k = 0; k < 512; k++) s += pb[k] * wfj[k];
  comb[j] = s;
  const float* hb  = hist + b * 48;
  const float* whj = wh + j * 48;
  float t = bh[j];
  for (int k = 0; k < 48; k++) t += hb[k] * whj[k];
  comb[64 + j] = t;
  __syncthreads();
  if (j < 3){
    float c = bo[j];
    const float* woj = wo + j * 128;
    for (int k = 0; k < 128; k++) c += comb[k] * woj[k];
    cfeat[b * 3 + j] = c;
  }
}

// ---------------- broadcast ----------------
__global__ __launch_bounds__(256) void bcast_k(const float* __restrict__ cfeat,
                                               float* __restrict__ out){
  size_t i = (size_t)blockIdx.x * 256 + threadIdx.x;
  int bc = (int)(i >> 14);
  float v = cfeat[bc];
  ((float4*)out)[i] = make_float4(v, v, v, v);
}

extern "C" void kernel_launch(void* const* d_in, const int* in_sizes, int n_in,
                              void* d_out, int out_size, void* d_ws, size_t ws_size,
                              hipStream_t stream){
  const float* img = (const float*)d_in[0];
  const float* w1  = (const float*)d_in[1];
  const float* b1  = (const float*)d_in[2];
  const float* w2  = (const float*)d_in[3];
  const float* b2  = (const float*)d_in[4];
  const float* w3  = (const float*)d_in[5];
  const float* b3  = (const float*)d_in[6];
  const float* w4  = (const float*)d_in[7];
  const float* b4  = (const float*)d_in[8];
  const float* wf  = (const float*)d_in[9];
  const float* bfv = (const float*)d_in[10];
  const float* wh  = (const float*)d_in[11];
  const float* bh  = (const float*)d_in[12];
  const float* wo  = (const float*)d_in[13];
  const float* bo  = (const float*)d_in[14];
  float* out = (float*)d_out;
  (void)in_sizes; (void)n_in; (void)out_size; (void)ws_size;

  char* ws = (char*)d_ws;
  size_t off = 0;
  auto alloc = [&](size_t bytes) -> void* {
    void* p = ws + off;
    off += (bytes + 255) & ~(size_t)255;
    return p;
  };
  constexpr int BC = 16;
  const size_t A1c  = (size_t)BC * 130 * 130 * 64 * 2;    // 34.6 MB
  const size_t A2c  = (size_t)BC * 66 * 66 * 128 * 2;     // 17.8 MB
  const size_t A4   = (size_t)64 * 16 * 16 * 512 * 2;     // 16.8 MB

  u16*   slot = (u16*)alloc(A1c);
  u16*   act2 = (u16*)alloc(A2c);
  u16*   imgr = act2;                                     // alias
  u16*   act4 = (u16*)alloc(A4);
  u16*   w1m  = (u16*)  alloc((size_t)64 * 64 * 2);
  u16*   w2r  = (u16*)  alloc((size_t)16 * 128 * 64 * 2);
  u16*   w3r  = (u16*)  alloc((size_t)16 * 256 * 128 * 2);
  u16*   w4r  = (u16*)  alloc((size_t)16 * 512 * 256 * 2);
  float* raw    = (float*)alloc((size_t)192 * 16 * 4);
  float* hist   = (float*)alloc((size_t)192 * 16 * 4);
  float* pooled = (float*)alloc((size_t)64 * 512 * 4);
  float* cfeat  = (float*)alloc((size_t)64 * 3 * 4);

  repack_w1m <<<dim3(16),   256, 0, stream>>>(w1, w1m);
  repack_w_bf<<<dim3(512),  256, 0, stream>>>(w2, w2r, 64, 128);
  repack_w_bf<<<dim3(2048), 256, 0, stream>>>(w3, w3r, 128, 256);
  repack_w_bf<<<dim3(8192), 256, 0, stream>>>(w4, w4r, 256, 512);

  hipMemsetAsync(raw, 0, 192 * 16 * 4, stream);
  hist_part<<<dim3(192, 8), 256, 0, stream>>>(img, raw);
  hist_finish<<<dim3(12), 256, 0, stream>>>(raw, hist);

  const int nH1 = 16 * (2 * 130 * 32 + 128 * 2 * 32);
  const int nH2 = 16 * (2 * 66 * 64 + 64 * 2 * 64);
  const int nH3 = 16 * (2 * 34 * 128 + 32 * 2 * 128);
  const int nHI = 16 * (2 * 258 * 2 + 256 * 2 * 2);

  for (int c = 0; c < 4; ++c){
    const float* img_c  = img  + (size_t)c * BC * 3 * 65536;
    u16*         act4_c = act4 + (size_t)c * BC * 256 * 512;

    halo_zero<<<dim3((nHI + 255) / 256), 256, 0, stream>>>(imgr, 16, 258, 258, 4);
    repack_img<<<dim3(4096), 256, 0, stream>>>(img_c, imgr);
    halo_zero<<<dim3((nH1 + 255) / 256), 256, 0, stream>>>(slot, 16, 130, 130, 64);
    conv1_mfma<<<dim3(1024), 256, 0, stream>>>(imgr, w1m, b1, slot);
    halo_zero<<<dim3((nH2 + 255) / 256), 256, 0, stream>>>(act2, 16, 66, 66, 128);  // imgr dead
    // conv2: M=65536, 64x128 tiles -> 1024 blocks (4/CU)
    conv_mfma<64, 128, 64, 64, 1, 1, 4, 4, 2>
        <<<dim3(1024, 1), 256, 0, stream>>>(slot, w2r, b2, act2);
    halo_zero<<<dim3((nH3 + 255) / 256), 256, 0, stream>>>(slot, 16, 34, 34, 256);  // act1 dead
    // conv3: M=16384, 64x128 tiles -> grid(256,2)=512 blocks
    conv_mfma<128, 256, 32, 32, 1, 1, 4, 4, 2>
        <<<dim3(256, 2), 256, 0, stream>>>(act2, w3r, b3, slot);
    // conv4: M=4096, 64x64 tiles -> grid(64,8)=512 blocks
    conv_mfma<256, 512, 16, 16, 0, 2, 2, 2, 2>
        <<<dim3(64, 8), 256, 0, stream>>>(slot, w4r, b4, act4_c);
  }

  pool_k<<<dim3(64), 512, 0, stream>>>(act4, pooled);
  feat_k<<<dim3(64), 64, 0, stream>>>(pooled, hist, wf, bfv, wh, bh, wo, bo, cfeat);
  bcast_k<<<dim3(12288), 256, 0, stream>>>(cfeat, out);
}